// Round 3
// baseline (25407.185 us; speedup 1.0000x reference)
//
#include <hip/hip_runtime.h>
#include <stdint.h>

#define S_LEN 8192
#define DIM   2048
#define W2    4096   // W row length = 2*DIM

typedef __attribute__((ext_vector_type(8))) __bf16 bf16x8;
typedef __attribute__((ext_vector_type(4))) float  floatx4;
typedef __attribute__((ext_vector_type(2))) float  f32x2;
typedef unsigned long long u64;
typedef unsigned int       u32;
typedef __attribute__((ext_vector_type(4))) u32 u32x4;

// ---------------------------------------------------------------------------
// Init: tag buffers. buf0 = s_0 = -1.0 with tag 0; buf1 tag 0 (never matches
// its first expected tag 1, so readers spin until written).
// ---------------------------------------------------------------------------
__global__ void init_pairs(u64* __restrict__ pairs) {
  int i = blockIdx.x * 256 + threadIdx.x;
  if (i < 2 * DIM) {
    pairs[i] = ((u64)__float_as_uint(-1.0f) << 32) | 0ull;
  }
}

// ---------------------------------------------------------------------------
// GEMM: C[m][n] = sum_k A[m][k] * W[n*4096 + 2048 + k] + b[n]
// (unchanged — correct, and small vs the recurrence)
// ---------------------------------------------------------------------------
__device__ inline bf16x8 pack_bf8(float4 a, float4 b) {
  bf16x8 h;
  h[0] = (__bf16)a.x; h[1] = (__bf16)a.y; h[2] = (__bf16)a.z; h[3] = (__bf16)a.w;
  h[4] = (__bf16)b.x; h[5] = (__bf16)b.y; h[6] = (__bf16)b.z; h[7] = (__bf16)b.w;
  return h;
}

__global__ __launch_bounds__(256) void gemm_ctx(const float* __restrict__ A,
                                                const float* __restrict__ W,
                                                const float* __restrict__ bias,
                                                float* __restrict__ C) {
  __shared__ __bf16 As[64][72];
  __shared__ __bf16 Bs[64][72];
  const int tid  = threadIdx.x;
  const int m0   = blockIdx.y * 64;
  const int n0   = blockIdx.x * 64;
  const int w    = tid >> 6;
  const int lane = tid & 63;
  const int wm   = w >> 1, wn = w & 1;
  const int r    = tid >> 2;
  const int seg  = tid & 3;

  floatx4 acc[2][2] = {};

  for (int k0 = 0; k0 < DIM; k0 += 64) {
    {
      const float* pa = A + (size_t)(m0 + r) * DIM + k0 + seg * 16;
      const float* pb = W + (size_t)(n0 + r) * W2 + DIM + k0 + seg * 16;
      float4 a0 = ((const float4*)pa)[0], a1 = ((const float4*)pa)[1];
      float4 a2 = ((const float4*)pa)[2], a3 = ((const float4*)pa)[3];
      float4 b0 = ((const float4*)pb)[0], b1 = ((const float4*)pb)[1];
      float4 b2 = ((const float4*)pb)[2], b3 = ((const float4*)pb)[3];
      *(bf16x8*)&As[r][seg * 16]     = pack_bf8(a0, a1);
      *(bf16x8*)&As[r][seg * 16 + 8] = pack_bf8(a2, a3);
      *(bf16x8*)&Bs[r][seg * 16]     = pack_bf8(b0, b1);
      *(bf16x8*)&Bs[r][seg * 16 + 8] = pack_bf8(b2, b3);
    }
    __syncthreads();
    #pragma unroll
    for (int kk = 0; kk < 64; kk += 32) {
      const int ks = kk + (lane >> 4) * 8;
      bf16x8 af[2], bfr[2];
      af[0]  = *(const bf16x8*)&As[32 * wm +      (lane & 15)][ks];
      af[1]  = *(const bf16x8*)&As[32 * wm + 16 + (lane & 15)][ks];
      bfr[0] = *(const bf16x8*)&Bs[32 * wn +      (lane & 15)][ks];
      bfr[1] = *(const bf16x8*)&Bs[32 * wn + 16 + (lane & 15)][ks];
      #pragma unroll
      for (int im = 0; im < 2; ++im)
        #pragma unroll
        for (int in = 0; in < 2; ++in)
          acc[im][in] = __builtin_amdgcn_mfma_f32_16x16x32_bf16(
              af[im], bfr[in], acc[im][in], 0, 0, 0);
    }
    __syncthreads();
  }

  #pragma unroll
  for (int in = 0; in < 2; ++in) {
    const int col = n0 + 32 * wn + 16 * in + (lane & 15);
    const float bv = bias[col];
    #pragma unroll
    for (int im = 0; im < 2; ++im) {
      const int rbase = m0 + 32 * wm + 16 * im + (lane >> 4) * 4;
      #pragma unroll
      for (int q = 0; q < 4; ++q)
        C[(size_t)(rbase + q) * DIM + col] = acc[im][in][q] + bv;
    }
  }
}

// ---------------------------------------------------------------------------
// Paired-tag poll: two 16B AGENT-scope loads (sc1 ONLY — v3's regression was
// sc0+sc1 = system scope), issued together, one wait. Each 8B word is
// {tag(lo32), value(hi32)}; 8B-aligned halves never tear, and max inter-WG
// skew is 1 step so any stale tag != want -> retry.
// ---------------------------------------------------------------------------
__device__ __forceinline__ void poll2(const u64* p, u32x4& r0, u32x4& r1) {
  asm volatile("global_load_dwordx4 %0, %2, off sc1\n\t"
               "global_load_dwordx4 %1, %3, off sc1\n\t"
               "s_waitcnt vmcnt(0)"
               : "=&v"(r0), "=&v"(r1)
               : "v"(p), "v"(p + 2)
               : "memory");
}

// ---------------------------------------------------------------------------
// Persistent recurrence v5: 64 WGs x 512 threads (8 waves). WG k owns rows
// [32k, 32k+32); wave w owns 4 rows; lane l owns cols [32l,32l+32).
// vs v4 (15.9ms):
//   - matvec in v_pk_fma_f32 (f32x2 vectors): 64 packed instr/lane instead
//     of 128 scalar -> VALU issue per SIMD 512->256 cy/step
//   - poll via 2x global_load_dwordx4 sc1 (agent scope, same semantics as
//     __hip_atomic_load AGENT RELAXED): half the poll issue/recheck cost
// ---------------------------------------------------------------------------
__global__ __launch_bounds__(512, 1) void recur(const float* __restrict__ W,
                                                const float* __restrict__ ce,
                                                float* __restrict__ out,
                                                u64* __restrict__ pairs) {
  __shared__ __align__(16) float st[2][DIM];
  const int tid = threadIdx.x;
  const int w = tid >> 6, l = tid & 63;
  const int i0 = blockIdx.x * 32;

  // W_state slab into registers: 4 rows x 16 float2 (32 cols) per lane
  f32x2 w2[4][16];
  #pragma unroll
  for (int r2 = 0; r2 < 4; ++r2) {
    const float* wp = W + (size_t)(i0 + 4 * w + r2) * W2 + 32 * l;
    #pragma unroll
    for (int j = 0; j < 8; ++j) {
      float4 v = ((const float4*)wp)[j];
      w2[r2][2 * j + 0] = (f32x2){v.x, v.y};
      w2[r2][2 * j + 1] = (f32x2){v.z, v.w};
    }
  }

  const int rmap  = ((l & 1) << 1) | ((l >> 1) & 1);  // row held after reduce
  const int myrow = i0 + 4 * w + rmap;                // valid when l < 4
  const bool owner = (l < 4);
  float hcm = -3.0e38f;              // running cummax
  float s_last = 0.f;
  u64* b0 = pairs;
  u64* b1 = pairs + DIM;
  const int base = tid * 4;          // 512 threads x 4 pairs = 2048
  // LDS store slot base (XOR swizzle, consistent with the rotated read)
  const int slot4 = (4 * tid) ^ (((tid >> 3) & 7) << 2);

  // step-1 operands (prefetched before the loop)
  float cev = 0.f, cxv = 0.f;
  if (owner) {
    cev = ce[myrow];
    cxv = out[myrow];
  }

  for (int t = 1; t <= S_LEN; ++t) {
    // ---- poll: all 2048 tags of s_{t-1} in buf[(t-1)&1] ----
    u64* src = ((t - 1) & 1) ? b1 : b0;
    const u32 want = (u32)(t - 1);
    const u64* pp = src + base;
    u32x4 r0, r1;
    poll2(pp, r0, r1);
    while (!((r0.x == want) & (r0.z == want) & (r1.x == want) & (r1.z == want)))
      poll2(pp, r0, r1);

    // ---- issue NEXT step's stream loads now; with the bare barrier below
    // they stay in flight and resolve during the next poll phase ----
    float ncev = 0.f, ncxv = 0.f;
    if (owner && t < S_LEN) {
      ncev = ce[(size_t)t * DIM + myrow];
      ncxv = out[(size_t)t * DIM + myrow];
    }

    // ---- broadcast via double-buffered LDS; values ride in the poll data ----
    float* stw = st[t & 1];
    {
      float4 sv4;
      sv4.x = __uint_as_float(r0.y);
      sv4.y = __uint_as_float(r0.w);
      sv4.z = __uint_as_float(r1.y);
      sv4.w = __uint_as_float(r1.w);
      *(float4*)&stw[slot4] = sv4;
    }
    // bare barrier: drain LDS only — vmem (prefetches, stores) stays in flight
    asm volatile("s_waitcnt lgkmcnt(0)\n\ts_barrier" ::: "memory");

    // ---- y partial: 4 rows x 32 cols per lane, packed dual-FP32 FMA ----
    f32x2 acc2[4] = {};
    #pragma unroll
    for (int jj = 0; jj < 8; ++jj) {
      const float4 sv = *(const float4*)&stw[32 * l + 4 * (jj ^ (l & 7))];
      const f32x2 s01 = (f32x2){sv.x, sv.y};
      const f32x2 s23 = (f32x2){sv.z, sv.w};
      #pragma unroll
      for (int r2 = 0; r2 < 4; ++r2) {
        acc2[r2] += w2[r2][2 * jj + 0] * s01;   // v_pk_fma_f32
        acc2[r2] += w2[r2][2 * jj + 1] * s23;   // v_pk_fma_f32
      }
    }
    float a0 = acc2[0].x + acc2[0].y;
    float a1 = acc2[1].x + acc2[1].y;
    float a2 = acc2[2].x + acc2[2].y;
    float a3 = acc2[3].x + acc2[3].y;

    // ---- reduce-scatter butterfly: 8 shfls total ----
    // L1 (xor 1): even lane keeps rows {0,1}, odd keeps rows {2,3}
    float u0 = (l & 1) ? a0 : a2;
    float u1 = (l & 1) ? a1 : a3;
    float x0 = __shfl_xor(u0, 1, 64);
    float x1 = __shfl_xor(u1, 1, 64);
    float c0 = ((l & 1) ? a2 : a0) + x0;
    float c1 = ((l & 1) ? a3 : a1) + x1;
    // L2 (xor 2): one value per lane, row = ((l&1)<<1)|((l>>1)&1)
    float uu = (l & 2) ? c0 : c1;
    float xx = __shfl_xor(uu, 2, 64);
    float d  = ((l & 2) ? c1 : c0) + xx;
    // L3..L6: plain butterfly on one value
    #pragma unroll
    for (int m = 4; m < 64; m <<= 1) d += __shfl_xor(d, m, 64);

    if (owner) {
      float y = d + cxv;
      hcm = fmaxf(hcm, cev);
      float e = __expf(-y);
      float s = hcm * __builtin_amdgcn_rcpf(1.0f + e);
      // tag store FIRST — it is the critical path for every other WG
      u64* dst = (t & 1) ? b1 : b0;
      u64 pk = ((u64)__float_as_uint(s) << 32) | (u64)(u32)t;
      __hip_atomic_store(&dst[myrow], pk, __ATOMIC_RELAXED,
                         __HIP_MEMORY_SCOPE_AGENT);
      asm volatile("" ::: "memory");  // keep result store behind the tag store
      out[(size_t)(t - 1) * DIM + myrow] = s;
      s_last = s;
    }
    cev = ncev;
    cxv = ncxv;
  }

  if (owner) out[(size_t)S_LEN * DIM + myrow] = s_last;
}

// ---------------------------------------------------------------------------
extern "C" void kernel_launch(void* const* d_in, const int* in_sizes, int n_in,
                              void* d_out, int out_size, void* d_ws, size_t ws_size,
                              hipStream_t stream) {
  const float* ce = (const float*)d_in[0];
  const float* W  = (const float*)d_in[1];
  const float* b  = (const float*)d_in[2];
  float* out = (float*)d_out;
  u64* pairs = (u64*)d_ws;   // 2 * 2048 * 8B = 32 KB

  hipLaunchKernelGGL(init_pairs, dim3(16), dim3(256), 0, stream, pairs);
  hipLaunchKernelGGL(gemm_ctx, dim3(DIM / 64, S_LEN / 64), dim3(256), 0, stream,
                     ce, W, b, out);
  hipLaunchKernelGGL(recur, dim3(64), dim3(512), 0, stream, W, ce, out, pairs);
}

// Round 4
// 15934.235 us; speedup vs baseline: 1.5945x; 1.5945x over previous
//
#include <hip/hip_runtime.h>
#include <stdint.h>

#define S_LEN 8192
#define DIM   2048
#define W2    4096   // W row length = 2*DIM

typedef __attribute__((ext_vector_type(8))) __bf16 bf16x8;
typedef __attribute__((ext_vector_type(4))) float  floatx4;
typedef __attribute__((ext_vector_type(2))) float  f32x2;
typedef unsigned long long u64;
typedef unsigned int       u32;

// ---------------------------------------------------------------------------
// Init: tag buffers. buf0 = s_0 = -1.0 with tag 0; buf1 tag 0 (never matches
// its first expected tag 1, so readers spin until written).
// ---------------------------------------------------------------------------
__global__ void init_pairs(u64* __restrict__ pairs) {
  int i = blockIdx.x * 256 + threadIdx.x;
  if (i < 2 * DIM) {
    pairs[i] = ((u64)__float_as_uint(-1.0f) << 32) | 0ull;
  }
}

// ---------------------------------------------------------------------------
// GEMM: C[m][n] = sum_k A[m][k] * W[n*4096 + 2048 + k] + b[n]
// (unchanged — correct, and small vs the recurrence)
// ---------------------------------------------------------------------------
__device__ inline bf16x8 pack_bf8(float4 a, float4 b) {
  bf16x8 h;
  h[0] = (__bf16)a.x; h[1] = (__bf16)a.y; h[2] = (__bf16)a.z; h[3] = (__bf16)a.w;
  h[4] = (__bf16)b.x; h[5] = (__bf16)b.y; h[6] = (__bf16)b.z; h[7] = (__bf16)b.w;
  return h;
}

__global__ __launch_bounds__(256) void gemm_ctx(const float* __restrict__ A,
                                                const float* __restrict__ W,
                                                const float* __restrict__ bias,
                                                float* __restrict__ C) {
  __shared__ __bf16 As[64][72];
  __shared__ __bf16 Bs[64][72];
  const int tid  = threadIdx.x;
  const int m0   = blockIdx.y * 64;
  const int n0   = blockIdx.x * 64;
  const int w    = tid >> 6;
  const int lane = tid & 63;
  const int wm   = w >> 1, wn = w & 1;
  const int r    = tid >> 2;
  const int seg  = tid & 3;

  floatx4 acc[2][2] = {};

  for (int k0 = 0; k0 < DIM; k0 += 64) {
    {
      const float* pa = A + (size_t)(m0 + r) * DIM + k0 + seg * 16;
      const float* pb = W + (size_t)(n0 + r) * W2 + DIM + k0 + seg * 16;
      float4 a0 = ((const float4*)pa)[0], a1 = ((const float4*)pa)[1];
      float4 a2 = ((const float4*)pa)[2], a3 = ((const float4*)pa)[3];
      float4 b0 = ((const float4*)pb)[0], b1 = ((const float4*)pb)[1];
      float4 b2 = ((const float4*)pb)[2], b3 = ((const float4*)pb)[3];
      *(bf16x8*)&As[r][seg * 16]     = pack_bf8(a0, a1);
      *(bf16x8*)&As[r][seg * 16 + 8] = pack_bf8(a2, a3);
      *(bf16x8*)&Bs[r][seg * 16]     = pack_bf8(b0, b1);
      *(bf16x8*)&Bs[r][seg * 16 + 8] = pack_bf8(b2, b3);
    }
    __syncthreads();
    #pragma unroll
    for (int kk = 0; kk < 64; kk += 32) {
      const int ks = kk + (lane >> 4) * 8;
      bf16x8 af[2], bfr[2];
      af[0]  = *(const bf16x8*)&As[32 * wm +      (lane & 15)][ks];
      af[1]  = *(const bf16x8*)&As[32 * wm + 16 + (lane & 15)][ks];
      bfr[0] = *(const bf16x8*)&Bs[32 * wn +      (lane & 15)][ks];
      bfr[1] = *(const bf16x8*)&Bs[32 * wn + 16 + (lane & 15)][ks];
      #pragma unroll
      for (int im = 0; im < 2; ++im)
        #pragma unroll
        for (int in = 0; in < 2; ++in)
          acc[im][in] = __builtin_amdgcn_mfma_f32_16x16x32_bf16(
              af[im], bfr[in], acc[im][in], 0, 0, 0);
    }
    __syncthreads();
  }

  #pragma unroll
  for (int in = 0; in < 2; ++in) {
    const int col = n0 + 32 * wn + 16 * in + (lane & 15);
    const float bv = bias[col];
    #pragma unroll
    for (int im = 0; im < 2; ++im) {
      const int rbase = m0 + 32 * wm + 16 * im + (lane >> 4) * 4;
      #pragma unroll
      for (int q = 0; q < 4; ++q)
        C[(size_t)(rbase + q) * DIM + col] = acc[im][in][q] + bv;
    }
  }
}

// ---------------------------------------------------------------------------
// Persistent recurrence v6: 64 WGs x 512 threads (8 waves). WG k owns rows
// [32k, 32k+32); wave w owns 4 rows; lane l owns cols [32l,32l+32).
// vs v4 (15.86ms): matvec in v_pk_fma_f32 only. POLL IS v4's EXACT FORM —
// both attempts to change its instruction form regressed via FETCH_SIZE
// blowup (v3 sc0sc1: +134MB, v5 dwordx4 sc1: +260MB). The compiler's 8B
// agent-scope atomic load gets an IC-friendly path the wide loads don't.
// DO NOT TOUCH THE POLL FORM.
// ---------------------------------------------------------------------------
__global__ __launch_bounds__(512, 1) void recur(const float* __restrict__ W,
                                                const float* __restrict__ ce,
                                                float* __restrict__ out,
                                                u64* __restrict__ pairs) {
  __shared__ __align__(16) float st[2][DIM];
  const int tid = threadIdx.x;
  const int w = tid >> 6, l = tid & 63;
  const int i0 = blockIdx.x * 32;

  // W_state slab into registers: 4 rows x 16 float2 (32 cols) per lane
  f32x2 w2[4][16];
  #pragma unroll
  for (int r2 = 0; r2 < 4; ++r2) {
    const float* wp = W + (size_t)(i0 + 4 * w + r2) * W2 + 32 * l;
    #pragma unroll
    for (int j = 0; j < 8; ++j) {
      float4 v = ((const float4*)wp)[j];
      w2[r2][2 * j + 0] = (f32x2){v.x, v.y};
      w2[r2][2 * j + 1] = (f32x2){v.z, v.w};
    }
  }

  const int rmap  = ((l & 1) << 1) | ((l >> 1) & 1);  // row held after reduce
  const int myrow = i0 + 4 * w + rmap;                // valid when l < 4
  const bool owner = (l < 4);
  float hcm = -3.0e38f;              // running cummax
  float s_last = 0.f;
  u64* b0 = pairs;
  u64* b1 = pairs + DIM;
  const int base = tid * 4;          // 512 threads x 4 entries = 2048
  // LDS store slot base (XOR swizzle, consistent with the rotated read)
  const int slot4 = (4 * tid) ^ (((tid >> 3) & 7) << 2);

  // step-1 operands (prefetched before the loop)
  float cev = 0.f, cxv = 0.f;
  if (owner) {
    cev = ce[myrow];
    cxv = out[myrow];
  }

  for (int t = 1; t <= S_LEN; ++t) {
    // ---- poll: all 2048 tags of s_{t-1} in buf[(t-1)&1] ----
    u64* src = ((t - 1) & 1) ? b1 : b0;
    const u32 want = (u32)(t - 1);
    u64 v[4];
    #pragma unroll
    for (int q = 0; q < 4; ++q)
      v[q] = __hip_atomic_load(&src[base + q], __ATOMIC_RELAXED,
                               __HIP_MEMORY_SCOPE_AGENT);
    for (;;) {
      u32 bad = 0;
      #pragma unroll
      for (int q = 0; q < 4; ++q)
        bad |= ((u32)v[q] != want) ? (1u << q) : 0u;
      if (!bad) break;
      #pragma unroll
      for (int q = 0; q < 4; ++q)
        if ((bad >> q) & 1u)
          v[q] = __hip_atomic_load(&src[base + q], __ATOMIC_RELAXED,
                                   __HIP_MEMORY_SCOPE_AGENT);
    }

    // ---- issue NEXT step's stream loads now; with the bare barrier below
    // they stay in flight and resolve during the next poll phase ----
    float ncev = 0.f, ncxv = 0.f;
    if (owner && t < S_LEN) {
      ncev = ce[(size_t)t * DIM + myrow];
      ncxv = out[(size_t)t * DIM + myrow];
    }

    // ---- broadcast via double-buffered LDS; values ride in the poll data ----
    float* stw = st[t & 1];
    {
      float4 sv4;
      sv4.x = __uint_as_float((u32)(v[0] >> 32));
      sv4.y = __uint_as_float((u32)(v[1] >> 32));
      sv4.z = __uint_as_float((u32)(v[2] >> 32));
      sv4.w = __uint_as_float((u32)(v[3] >> 32));
      *(float4*)&stw[slot4] = sv4;
    }
    // bare barrier: drain LDS only — vmem (prefetches, stores) stays in flight
    asm volatile("s_waitcnt lgkmcnt(0)\n\ts_barrier" ::: "memory");

    // ---- y partial: 4 rows x 32 cols per lane, packed dual-FP32 FMA ----
    f32x2 acc2[4] = {};
    #pragma unroll
    for (int jj = 0; jj < 8; ++jj) {
      const float4 sv = *(const float4*)&stw[32 * l + 4 * (jj ^ (l & 7))];
      const f32x2 s01 = (f32x2){sv.x, sv.y};
      const f32x2 s23 = (f32x2){sv.z, sv.w};
      #pragma unroll
      for (int r2 = 0; r2 < 4; ++r2) {
        acc2[r2] += w2[r2][2 * jj + 0] * s01;   // v_pk_fma_f32
        acc2[r2] += w2[r2][2 * jj + 1] * s23;   // v_pk_fma_f32
      }
    }
    float a0 = acc2[0].x + acc2[0].y;
    float a1 = acc2[1].x + acc2[1].y;
    float a2 = acc2[2].x + acc2[2].y;
    float a3 = acc2[3].x + acc2[3].y;

    // ---- reduce-scatter butterfly: 8 shfls total ----
    // L1 (xor 1): even lane keeps rows {0,1}, odd keeps rows {2,3}
    float u0 = (l & 1) ? a0 : a2;
    float u1 = (l & 1) ? a1 : a3;
    float x0 = __shfl_xor(u0, 1, 64);
    float x1 = __shfl_xor(u1, 1, 64);
    float c0 = ((l & 1) ? a2 : a0) + x0;
    float c1 = ((l & 1) ? a3 : a1) + x1;
    // L2 (xor 2): one value per lane, row = ((l&1)<<1)|((l>>1)&1)
    float uu = (l & 2) ? c0 : c1;
    float xx = __shfl_xor(uu, 2, 64);
    float d  = ((l & 2) ? c1 : c0) + xx;
    // L3..L6: plain butterfly on one value
    #pragma unroll
    for (int m = 4; m < 64; m <<= 1) d += __shfl_xor(d, m, 64);

    if (owner) {
      float y = d + cxv;
      hcm = fmaxf(hcm, cev);
      float e = __expf(-y);
      float s = hcm * __builtin_amdgcn_rcpf(1.0f + e);
      // tag store FIRST — it is the critical path for every other WG
      u64* dst = (t & 1) ? b1 : b0;
      u64 pk = ((u64)__float_as_uint(s) << 32) | (u64)(u32)t;
      __hip_atomic_store(&dst[myrow], pk, __ATOMIC_RELAXED,
                         __HIP_MEMORY_SCOPE_AGENT);
      asm volatile("" ::: "memory");  // keep result store behind the tag store
      out[(size_t)(t - 1) * DIM + myrow] = s;
      s_last = s;
    }
    cev = ncev;
    cxv = ncxv;
  }

  if (owner) out[(size_t)S_LEN * DIM + myrow] = s_last;
}

// ---------------------------------------------------------------------------
extern "C" void kernel_launch(void* const* d_in, const int* in_sizes, int n_in,
                              void* d_out, int out_size, void* d_ws, size_t ws_size,
                              hipStream_t stream) {
  const float* ce = (const float*)d_in[0];
  const float* W  = (const float*)d_in[1];
  const float* b  = (const float*)d_in[2];
  float* out = (float*)d_out;
  u64* pairs = (u64*)d_ws;   // 2 * 2048 * 8B = 32 KB

  hipLaunchKernelGGL(init_pairs, dim3(16), dim3(256), 0, stream, pairs);
  hipLaunchKernelGGL(gemm_ctx, dim3(DIM / 64, S_LEN / 64), dim3(256), 0, stream,
                     ce, W, b, out);
  hipLaunchKernelGGL(recur, dim3(64), dim3(512), 0, stream, W, ce, out, pairs);
}